// Round 2
// baseline (18886.609 us; speedup 1.0000x reference)
//
#include <hip/hip_runtime.h>
#include <hip/hip_bf16.h>
#include <hip/hip_cooperative_groups.h>
#include <math.h>

namespace cg = cooperative_groups;

typedef short bfrag8 __attribute__((ext_vector_type(8)));   // 8 bf16 (4 VGPRs)
typedef float facc4  __attribute__((ext_vector_type(4)));   // MFMA accumulator

#define BATCH   128
#define TSTEPS  256
#define UNITS   1024

// ---------------------------------------------------------------------------
// Packed weight layout: packed row p in [0,4096): ut=p>>5, g=(p>>3)&3, j=p&7,
// u = ut*8+j.  gate g: 0=z (Wx col u + Wh col u stacked over k), 1=r (+1024),
// 2=xh (Wx only, k<Din), 3=rh (Wh only, k>=Din).  W[p][k], k-contiguous,
// K = Din+1024 (1152 for layer 0, 2048 otherwise). bf16 (hi-only).
// ---------------------------------------------------------------------------

struct GArgs {
  const __hip_bfloat16* xin;      // [T][B][128] layer-0 input
  const __hip_bfloat16* Wp[4];    // packed weights [4096][KS_l]
  const float* pb;                // packed biases [4][4096]
  __hip_bfloat16* hout;           // h outputs [4][2(parity)][B*U] bf16
  float* hf;                      // fp32 h state [4][B*U] (in-place)
  const float* Wd;                // [1024]
  const float* bd;                // [1]
  float* out;                     // [128]
};

// ---------------------------------------------------------------------------
__global__ void prep_xin(const float* __restrict__ in, __hip_bfloat16* __restrict__ xin) {
  int idx = blockIdx.x * 256 + threadIdx.x;          // over xin[t][b][d]
  if (idx >= TSTEPS * BATCH * 128) return;
  int d = idx & 127;
  int b = (idx >> 7) & 127;
  int t = idx >> 14;
  xin[idx] = __float2bfloat16(in[((size_t)b * TSTEPS + t) * 128 + d]);
}

__global__ void prep_w(const float* __restrict__ Wx, const float* __restrict__ Wh,
                       int Din, int KS, __hip_bfloat16* __restrict__ W) {
  const int p = blockIdx.x;                // packed row, 0..4095
  const int tid = threadIdx.x;
  const int g = (p >> 3) & 3, j = p & 7;
  const int u = (p >> 5) * 8 + j;
  const int col = (g == 0) ? u : (g == 1) ? (1024 + u) : (2048 + u);
  const size_t base = (size_t)p * KS;
  #pragma unroll
  for (int e = 0; e < 8; ++e) {
    const int k = (tid << 3) + e;
    if (k >= KS) break;
    float v = 0.0f;
    if (k < Din) { if (g != 3) v = Wx[(size_t)k * 3072 + col]; }
    else         { if (g != 2) v = Wh[(size_t)(k - Din) * 3072 + col]; }
    W[base + k] = __float2bfloat16(v);
  }
}

struct BiasArgs { const float* bx[4]; const float* bh[4]; float* pb; };

__global__ void prep_bias(BiasArgs ba) {
  int idx = blockIdx.x * 256 + threadIdx.x;          // l*4096 + p
  if (idx >= 4 * 4096) return;
  int p = idx & 4095, l = idx >> 12;
  int g = (p >> 3) & 3, j = p & 7;
  int u = (p >> 5) * 8 + j;
  const float* bx = ba.bx[l];
  const float* bh = ba.bh[l];
  float v;
  if (g == 0)      v = bx[u] + bh[u];
  else if (g == 1) v = bx[1024 + u] + bh[1024 + u];
  else if (g == 2) v = bx[2048 + u];
  else             v = bh[2048 + u];
  ba.pb[idx] = v;
}

// ---------------------------------------------------------------------------
// Layer-pipelined cooperative kernel. Grid 256 WGs x 256 thr.
// wg = l*64 + nt : layer l handles t = s - l at global step s (259 steps).
// WG tile: M=128 (full batch) x N=64 packed cols (16 units), BK=64.
// 4 waves = 2m x 2n; wave tile 64m x 32n -> 4x2 facc4 accumulators.
// One grid.sync per step; h state double-buffered by step parity.
// ---------------------------------------------------------------------------
__global__ __launch_bounds__(256) void gru_pipe(GArgs g) {
  cg::grid_group grid = cg::this_grid();
  __shared__ uint4 lsA4[2][1024];          // A tile [buf][128 rows][8 chunks], XOR-swizzled
  __shared__ uint4 lsB4[2][512];           // B tile [buf][64 rows][8 chunks], XOR-swizzled
  __shared__ float lsC[128 * 66];          // C scratch (pad 66 breaks bank alignment)
  const short* lsA = (const short*)lsA4;
  const short* lsB = (const short*)lsB4;

  const int tid  = threadIdx.x;
  const int lane = tid & 63;
  const int wave = tid >> 6;
  const int wm = wave >> 1, wn = wave & 1;
  const int wg = blockIdx.x;
  const int l  = wg >> 6;                  // layer 0..3
  const int nt = wg & 63;                  // n-tile
  const int p0 = nt << 6;                  // packed-col base
  const int Din = l ? UNITS : 128;
  const int KS  = Din + UNITS;             // 1152 or 2048
  const int NKT = KS >> 6;                 // 18 or 32 k-tiles
  const __hip_bfloat16* Wl = g.Wp[l];
  const float* pbL = g.pb + (l << 12);

  { // zero all h state (ws is re-poisoned before every launch)
    const uint4 z4 = {0, 0, 0, 0};
    uint4* hz = (uint4*)g.hout;            // 131072 chunks total
    uint4* fz = (uint4*)g.hf;              // 131072 chunks total
    #pragma unroll
    for (int i = 0; i < 2; ++i) {
      hz[(wg << 9) + (i << 8) + tid] = z4;
      fz[(wg << 9) + (i << 8) + tid] = z4;
    }
  }
  grid.sync();

  for (int s = 0; s < TSTEPS + 3; ++s) {
    const int t = s - l;
    if (t >= 0 && t < TSTEPS) {
      const __hip_bfloat16* xsrc = l
          ? (g.hout + (size_t)(((l - 1) << 1) | ((s - 1) & 1)) * (BATCH * UNITS))
          : (g.xin + (size_t)t * (BATCH * 128));
      const __hip_bfloat16* hsrc =
          g.hout + (size_t)((l << 1) | ((s - 1) & 1)) * (BATCH * UNITS);
      const int xstride = l ? UNITS : 128;

      uint4 ra[4]; uint4 rb[2];
      auto loadregs = [&](int kt) {        // issue global loads (latency hides under MFMA)
        const int k0 = kt << 6;
        const __hip_bfloat16* asrc; int rs;
        if (k0 < Din) { asrc = xsrc + k0;          rs = xstride; }
        else          { asrc = hsrc + (k0 - Din);  rs = UNITS; }
        #pragma unroll
        for (int i = 0; i < 4; ++i) {
          const int c = (i << 8) + tid;
          ra[i] = *(const uint4*)(asrc + (size_t)(c >> 3) * rs + ((c & 7) << 3));
        }
        #pragma unroll
        for (int i = 0; i < 2; ++i) {
          const int c = (i << 8) + tid;
          rb[i] = *(const uint4*)(Wl + (size_t)(p0 + (c >> 3)) * KS + k0 + ((c & 7) << 3));
        }
      };
      auto writeregs = [&](int buf) {      // T2 XOR-swizzled LDS writes
        #pragma unroll
        for (int i = 0; i < 4; ++i) {
          const int c = (i << 8) + tid, r = c >> 3;
          lsA4[buf][(r << 3) | ((c & 7) ^ (r & 7))] = ra[i];
        }
        #pragma unroll
        for (int i = 0; i < 2; ++i) {
          const int c = (i << 8) + tid, r = c >> 3;
          lsB4[buf][(r << 3) | ((c & 7) ^ (r & 7))] = rb[i];
        }
      };

      facc4 acc[4][2];
      #pragma unroll
      for (int fa = 0; fa < 4; ++fa)
        #pragma unroll
        for (int fb = 0; fb < 2; ++fb)
          acc[fa][fb] = (facc4){0, 0, 0, 0};

      loadregs(0);
      for (int kt = 0; kt < NKT; ++kt) {
        const int buf = kt & 1;
        writeregs(buf);
        if (kt + 1 < NKT) loadregs(kt + 1);
        __syncthreads();                   // buf visible; other buf free (sync of kt-1)
        #pragma unroll
        for (int kh = 0; kh < 2; ++kh) {
          const int kg = (kh << 2) | (lane >> 4);
          bfrag8 bfr[2];
          #pragma unroll
          for (int fb = 0; fb < 2; ++fb) {
            const int r = (wn << 5) + (fb << 4) + (lane & 15);
            bfr[fb] = *(const bfrag8*)&lsB[((buf << 9) + ((r << 3) | (kg ^ (r & 7)))) << 3];
          }
          #pragma unroll
          for (int fa = 0; fa < 4; ++fa) {
            const int r = (wm << 6) + (fa << 4) + (lane & 15);
            bfrag8 afr = *(const bfrag8*)&lsA[((buf << 10) + ((r << 3) | (kg ^ (r & 7)))) << 3];
            acc[fa][0] = __builtin_amdgcn_mfma_f32_16x16x32_bf16(afr, bfr[0], acc[fa][0], 0, 0, 0);
            acc[fa][1] = __builtin_amdgcn_mfma_f32_16x16x32_bf16(afr, bfr[1], acc[fa][1], 0, 0, 0);
          }
        }
      }

      { // C/D layout: col=lane&15 (B side), row=(lane>>4)*4+j (A side)  [m89]
        #pragma unroll
        for (int fa = 0; fa < 4; ++fa) {
          const int crow = (wm << 6) + (fa << 4) + ((lane >> 4) << 2);
          #pragma unroll
          for (int fb = 0; fb < 2; ++fb) {
            const int ccol = (wn << 5) + (fb << 4) + (lane & 15);
            #pragma unroll
            for (int j = 0; j < 4; ++j)
              lsC[(crow + j) * 66 + ccol] = acc[fa][fb][j];
          }
        }
      }
      __syncthreads();

      // pointwise GRU update: 128 m x 16 u per WG, 8 per thread
      float* hfL = g.hf + (size_t)l * (BATCH * UNITS);
      __hip_bfloat16* hdst =
          g.hout + (size_t)((l << 1) | (s & 1)) * (BATCH * UNITS);
      #pragma unroll
      for (int i = 0; i < 8; ++i) {
        const int q = (i << 8) + tid;
        const int m = q >> 4, ju = q & 15;
        const int cb = ((ju >> 3) << 5) + (ju & 7);
        const float gz  = lsC[m * 66 + cb]      + pbL[p0 + cb];
        const float gr  = lsC[m * 66 + cb + 8]  + pbL[p0 + cb + 8];
        const float gxh = lsC[m * 66 + cb + 16] + pbL[p0 + cb + 16];
        const float grh = lsC[m * 66 + cb + 24] + pbL[p0 + cb + 24];
        const float z = 1.0f / (1.0f + __expf(-gz));
        const float r = 1.0f / (1.0f + __expf(-gr));
        const float e2 = __expf(2.0f * (gxh + r * grh));
        const float hh = 1.0f - 2.0f / (e2 + 1.0f);   // tanh
        const int mu = m * UNITS + (nt << 4) + ju;
        const float hn = z * hfL[mu] + (1.0f - z) * hh;
        hfL[mu] = hn;
        hdst[mu] = __float2bfloat16(hn);
      }
    }
    grid.sync();                           // h(t) of every layer visible grid-wide
  }

  // dense head: out[b] = hf[3][b][:] . Wd + bd
  if (wg < BATCH) {
    const float* h = g.hf + (size_t)3 * (BATCH * UNITS) + (size_t)wg * UNITS;
    float ssum = 0.0f;
    for (int u = tid; u < UNITS; u += 256) ssum += h[u] * g.Wd[u];
    lsC[tid] = ssum;
    __syncthreads();
    for (int off = 128; off; off >>= 1) {
      if (tid < off) lsC[tid] += lsC[tid + off];
      __syncthreads();
    }
    if (tid == 0) g.out[wg] = lsC[0] + g.bd[0];
  }
}

// ---------------------------------------------------------------------------
extern "C" void kernel_launch(void* const* d_in, const int* in_sizes, int n_in,
                              void* d_out, int out_size, void* d_ws, size_t ws_size,
                              hipStream_t stream) {
  (void)in_sizes; (void)n_in; (void)out_size; (void)ws_size;
  const float* inputs = (const float*)d_in[0];
  const float* Wx[4] = {(const float*)d_in[1], (const float*)d_in[5], (const float*)d_in[9],  (const float*)d_in[13]};
  const float* Wh[4] = {(const float*)d_in[2], (const float*)d_in[6], (const float*)d_in[10], (const float*)d_in[14]};
  const float* bx[4] = {(const float*)d_in[3], (const float*)d_in[7], (const float*)d_in[11], (const float*)d_in[15]};
  const float* bh[4] = {(const float*)d_in[4], (const float*)d_in[8], (const float*)d_in[12], (const float*)d_in[16]};
  const float* Wd = (const float*)d_in[17];
  const float* bd = (const float*)d_in[18];

  char* w = (char*)d_ws;
  auto alloc = [&](size_t bytes) {
    char* p = w;
    w += (bytes + 255) & ~(size_t)255;
    return p;
  };
  // total ~72.4 MiB (vs round-1's 265.6 MiB workspace-overflow crash)
  __hip_bfloat16* xin = (__hip_bfloat16*)alloc((size_t)TSTEPS * BATCH * 128 * 2);
  __hip_bfloat16* Wp[4];
  Wp[0] = (__hip_bfloat16*)alloc((size_t)4096 * 1152 * 2);
  for (int l = 1; l < 4; ++l)
    Wp[l] = (__hip_bfloat16*)alloc((size_t)4096 * 2048 * 2);
  __hip_bfloat16* hout = (__hip_bfloat16*)alloc((size_t)4 * 2 * BATCH * UNITS * 2);
  float* hf = (float*)alloc((size_t)4 * BATCH * UNITS * 4);
  float* pb = (float*)alloc((size_t)4 * 4096 * 4);

  prep_xin<<<(TSTEPS * BATCH * 128) / 256, 256, 0, stream>>>(inputs, xin);
  for (int l = 0; l < 4; ++l) {
    const int Din = (l == 0) ? 128 : 1024;
    prep_w<<<4096, 256, 0, stream>>>(Wx[l], Wh[l], Din, Din + 1024, Wp[l]);
  }
  BiasArgs ba;
  for (int l = 0; l < 4; ++l) { ba.bx[l] = bx[l]; ba.bh[l] = bh[l]; }
  ba.pb = pb;
  prep_bias<<<64, 256, 0, stream>>>(ba);

  GArgs ga;
  ga.xin = xin;
  for (int l = 0; l < 4; ++l) ga.Wp[l] = Wp[l];
  ga.pb = pb;
  ga.hout = hout;
  ga.hf = hf;
  ga.Wd = Wd;
  ga.bd = bd;
  ga.out = (float*)d_out;

  void* kargs[] = { &ga };
  hipLaunchCooperativeKernel((const void*)gru_pipe, dim3(256), dim3(256), kargs, 0, stream);
}

// Round 3
// 15094.043 us; speedup vs baseline: 1.2513x; 1.2513x over previous
//
#include <hip/hip_runtime.h>
#include <hip/hip_bf16.h>
#include <hip/hip_cooperative_groups.h>
#include <math.h>

namespace cg = cooperative_groups;

typedef short bfrag8 __attribute__((ext_vector_type(8)));   // 8 bf16 (4 VGPRs)
typedef float facc4  __attribute__((ext_vector_type(4)));   // MFMA accumulator

#define BATCH   128
#define TSTEPS  256
#define UNITS   1024

// ---------------------------------------------------------------------------
// All GEMM operands are consumed straight from global (L2/L3-resident) in
// MFMA fragment order — no LDS staging (round-2 showed 1.32e9 LDS bank-
// conflict cycles + barrier-serialized staging at 1 WG/CU).
//
// B (weights), packed by prep_w per layer into streaming order:
//   [nt(64)][kt(NKT)][wn(2)][kh(2)][fb(2)][lane(64)][8 bf16]
//   lane holds B[row = nt*64 + wn*32 + fb*16 + (lane&15)]
//               [k   = kt*64 + (kh*4 + (lane>>4))*8 + 0..7]
//   B-row r in an nt-block: uh=r>>5, g=(r>>3)&3, eu=r&7 -> unit u=nt*16+uh*8+eu
//   gate g: 0=z (Wx+Wh col u), 1=r (+1024), 2=xh (Wx only), 3=rh (Wh only)
//
// A (x / h state), chunk-major: [k-chunk gk][m(128)][8 bf16]  (chunk = 8 k)
// ---------------------------------------------------------------------------

struct GArgs {
  const __hip_bfloat16* xin;      // [T][16 chunks][128][8] layer-0 input
  const __hip_bfloat16* Wp[4];    // packed weights (layout above)
  const float* pb;                // packed biases [4][4096] (B-row order)
  __hip_bfloat16* hout;           // h out [4][2 parity][128 chunks][128][8]
  float* hf;                      // fp32 h state [4][128][1024] (in-place)
  const float* Wd;                // [1024]
  const float* bd;                // [1]
  float* out;                     // [128]
};

// ---------------------------------------------------------------------------
__global__ void prep_xin(const float* __restrict__ in, __hip_bfloat16* __restrict__ xin) {
  const int idx = blockIdx.x * 256 + threadIdx.x;    // chunk id: (t, kg, m)
  if (idx >= TSTEPS * 16 * 128) return;
  const int m  = idx & 127;
  const int kg = (idx >> 7) & 15;
  const int t  = idx >> 11;
  union { __hip_bfloat16 h[8]; uint4 v; } o;
  const float* src = in + ((size_t)m * TSTEPS + t) * 128 + (kg << 3);
  #pragma unroll
  for (int e = 0; e < 8; ++e) o.h[e] = __float2bfloat16(src[e]);
  ((uint4*)xin)[idx] = o.v;
}

__global__ void prep_w(const float* __restrict__ Wx, const float* __restrict__ Wh,
                       int Din, int KS, int NKT, __hip_bfloat16* __restrict__ W) {
  const int p   = blockIdx.x;              // global B-row, 0..4095
  const int tid = threadIdx.x;             // k-chunk along K
  const int k0  = tid << 3;
  if (k0 >= KS) return;
  const int nt = p >> 6, r = p & 63;
  const int wn = r >> 5, fb = (r >> 4) & 1, rl = r & 15;
  const int gg = (r >> 3) & 3, eu = r & 7;
  const int u   = nt * 16 + wn * 8 + eu;   // uh == wn by construction
  const int col = (gg == 0) ? u : (gg == 1) ? (1024 + u) : (2048 + u);
  const int kt = tid >> 3, c = tid & 7, kh = c >> 2, kq = c & 3;
  const int lane = kq * 16 + rl;
  union { __hip_bfloat16 h[8]; uint4 v; } o;
  #pragma unroll
  for (int e = 0; e < 8; ++e) {
    const int k = k0 + e;
    float v = 0.0f;
    if (k < Din) { if (gg != 3) v = Wx[(size_t)k * 3072 + col]; }
    else         { if (gg != 2) v = Wh[(size_t)(k - Din) * 3072 + col]; }
    o.h[e] = __float2bfloat16(v);
  }
  const size_t off16 = (size_t)nt * (NKT * 512)
                     + (size_t)(((kt * 2 + wn) * 2 + kh) * 2 + fb) * 64 + lane;
  ((uint4*)W)[off16] = o.v;
}

struct BiasArgs { const float* bx[4]; const float* bh[4]; float* pb; };

__global__ void prep_bias(BiasArgs ba) {
  const int idx = blockIdx.x * 256 + threadIdx.x;    // l*4096 + p
  if (idx >= 4 * 4096) return;
  const int p = idx & 4095, l = idx >> 12;
  const int nt = p >> 6, r = p & 63;
  const int uh = r >> 5, g = (r >> 3) & 3, eu = r & 7;
  const int u = nt * 16 + uh * 8 + eu;
  const float* bx = ba.bx[l];
  const float* bh = ba.bh[l];
  float v;
  if (g == 0)      v = bx[u] + bh[u];
  else if (g == 1) v = bx[1024 + u] + bh[1024 + u];
  else if (g == 2) v = bx[2048 + u];
  else             v = bh[2048 + u];
  ba.pb[idx] = v;
}

// ---------------------------------------------------------------------------
// Layer-pipelined cooperative kernel. Grid 256 WGs x 256 thr, 1 WG/CU.
// wg = l*64 + nt : layer l handles t = s - l at global step s (259 steps).
// WG tile M=128 x N=64 (B-rows); 4 waves 2m x 2n, wave tile 64m x 32n.
// k-loop: barrier-free, direct-to-VGPR fragment loads, 2-deep reg pipeline.
// ---------------------------------------------------------------------------
__global__ __launch_bounds__(256) void gru_pipe(GArgs g) {
  cg::grid_group grid = cg::this_grid();
  __shared__ float lsC[128 * 66];          // C scratch only (33.8 KB)

  const int tid  = threadIdx.x;
  const int lane = tid & 63;
  const int wave = tid >> 6;
  const int wm = wave >> 1, wn = wave & 1;
  const int wg = blockIdx.x;
  const int l  = wg >> 6;                  // layer 0..3
  const int nt = wg & 63;                  // n-tile (16 units)
  const int NKT  = l ? 32 : 18;            // k-tiles of 64
  const int DINC = l ? 128 : 16;           // x-part k-chunks (Din/8)
  const float* pbL = g.pb + (l << 12) + (nt << 6);
  const int r15 = lane & 15;
  const int kq  = lane >> 4;

  // B stream base for this (WG, wave): + kt*8192 + kh*2048 + fb*1024 later
  const char* Bbase = (const char*)g.Wp[l]
                    + (size_t)nt * NKT * 8192 + (size_t)wn * 4096 + (size_t)lane * 16;
  // A fragment row offsets (bytes within a chunk's [128][8] block)
  int aoff[4];
  #pragma unroll
  for (int fa = 0; fa < 4; ++fa) aoff[fa] = (wm * 64 + fa * 16 + r15) * 16;

  { // zero h state (hout 2 MB + hf 2 MB; ws is poisoned before every launch)
    const uint4 z4 = {0, 0, 0, 0};
    uint4* hz = (uint4*)g.hout;
    uint4* fz = (uint4*)g.hf;
    #pragma unroll
    for (int i = 0; i < 2; ++i) {
      hz[(wg << 9) + (i << 8) + tid] = z4;
      fz[(wg << 9) + (i << 8) + tid] = z4;
    }
  }
  grid.sync();

  for (int s = 0; s < TSTEPS + 3; ++s) {
    const int t = s - l;
    if (t >= 0 && t < TSTEPS) {
      const __hip_bfloat16* xA = l
          ? (g.hout + (size_t)(((l - 1) << 1) | ((s - 1) & 1)) * (128 * 1024))
          : (g.xin + (size_t)t * (16 * 128 * 8));
      const __hip_bfloat16* hA =
          g.hout + (size_t)((l << 1) | ((s - 1) & 1)) * (128 * 1024);

      bfrag8 aP[8], bP[4], aQ[8], bQ[4];

      // one k-tile's 12 fragment loads (8 A + 4 B), all independent
      #define LOADAB(AR, BR, KT)                                               \
        {                                                                      \
          const int kt_ = (KT);                                                \
          _Pragma("unroll")                                                    \
          for (int kh = 0; kh < 2; ++kh) {                                     \
            const int gk = kt_ * 8 + kh * 4 + kq;                              \
            const char* src = (gk < DINC)                                      \
                ? ((const char*)xA + (size_t)gk * 2048)                        \
                : ((const char*)hA + (size_t)(gk - DINC) * 2048);              \
            _Pragma("unroll")                                                  \
            for (int fa = 0; fa < 4; ++fa)                                     \
              AR[kh * 4 + fa] = *(const bfrag8*)(src + aoff[fa]);              \
            _Pragma("unroll")                                                  \
            for (int fb = 0; fb < 2; ++fb)                                     \
              BR[kh * 2 + fb] = *(const bfrag8*)(Bbase + (size_t)kt_ * 8192    \
                                                 + kh * 2048 + fb * 1024);     \
          }                                                                    \
        }

      #define DOMFMA(AR, BR)                                                   \
        _Pragma("unroll")                                                      \
        for (int kh = 0; kh < 2; ++kh) {                                       \
          _Pragma("unroll")                                                    \
          for (int fa = 0; fa < 4; ++fa) {                                     \
            acc[fa][0] = __builtin_amdgcn_mfma_f32_16x16x32_bf16(              \
                AR[kh * 4 + fa], BR[kh * 2 + 0], acc[fa][0], 0, 0, 0);         \
            acc[fa][1] = __builtin_amdgcn_mfma_f32_16x16x32_bf16(              \
                AR[kh * 4 + fa], BR[kh * 2 + 1], acc[fa][1], 0, 0, 0);         \
          }                                                                    \
        }

      facc4 acc[4][2];
      #pragma unroll
      for (int fa = 0; fa < 4; ++fa)
        #pragma unroll
        for (int fb = 0; fb < 2; ++fb)
          acc[fa][fb] = (facc4){0, 0, 0, 0};

      LOADAB(aP, bP, 0);
      for (int kt = 0; kt < NKT; kt += 2) {    // NKT even (18 or 32)
        LOADAB(aQ, bQ, kt + 1);
        DOMFMA(aP, bP);
        if (kt + 2 < NKT) LOADAB(aP, bP, kt + 2);
        DOMFMA(aQ, bQ);
      }
      #undef LOADAB
      #undef DOMFMA

      { // C/D layout: col=lane&15 (B side), row=(lane>>4)*4+j (A side)  [m89]
        #pragma unroll
        for (int fa = 0; fa < 4; ++fa) {
          const int crow = (wm << 6) + (fa << 4) + ((lane >> 4) << 2);
          #pragma unroll
          for (int fb = 0; fb < 2; ++fb) {
            const int ccol = (wn << 5) + (fb << 4) + r15;
            #pragma unroll
            for (int j = 0; j < 4; ++j)
              lsC[(crow + j) * 66 + ccol] = acc[fa][fb][j];
          }
        }
      }
      __syncthreads();

      // pointwise GRU: thread -> (m = tid&127, blk = tid>>7), 8 units each
      {
        float* hfL = g.hf + (size_t)l * (BATCH * 1024);
        __hip_bfloat16* houtW =
            g.hout + (size_t)((l << 1) | (s & 1)) * (128 * 1024);
        const int m = tid & 127;
        const int blk = tid >> 7;            // 0..1
        const float* cr  = lsC + m * 66 + blk * 32;
        const float* pbb = pbL + blk * 32;
        union { __hip_bfloat16 h[8]; uint4 v; } ou;
        #pragma unroll
        for (int e = 0; e < 8; ++e) {
          const float gz  = cr[e]      + pbb[e];
          const float gr  = cr[8 + e]  + pbb[8 + e];
          const float gxh = cr[16 + e] + pbb[16 + e];
          const float grh = cr[24 + e] + pbb[24 + e];
          const float z = 1.0f / (1.0f + __expf(-gz));
          const float r = 1.0f / (1.0f + __expf(-gr));
          const float e2 = __expf(2.0f * (gxh + r * grh));
          const float hh = 1.0f - 2.0f / (e2 + 1.0f);   // tanh
          const int iu = m * 1024 + (nt << 4) + (blk << 3) + e;
          const float hn = z * hfL[iu] + (1.0f - z) * hh;
          hfL[iu] = hn;
          ou.h[e] = __float2bfloat16(hn);
        }
        ((uint4*)houtW)[(nt * 2 + blk) * 128 + m] = ou.v;
      }
    }
    grid.sync();                           // h(t) of every layer visible
  }

  // dense head: out[b] = hf[3][b][:] . Wd + bd
  if (wg < BATCH) {
    const float* h = g.hf + (size_t)3 * (BATCH * 1024) + (size_t)wg * 1024;
    float ssum = 0.0f;
    for (int u = tid; u < UNITS; u += 256) ssum += h[u] * g.Wd[u];
    lsC[tid] = ssum;
    __syncthreads();
    for (int off = 128; off; off >>= 1) {
      if (tid < off) lsC[tid] += lsC[tid + off];
      __syncthreads();
    }
    if (tid == 0) g.out[wg] = lsC[0] + g.bd[0];
  }
}

// ---------------------------------------------------------------------------
extern "C" void kernel_launch(void* const* d_in, const int* in_sizes, int n_in,
                              void* d_out, int out_size, void* d_ws, size_t ws_size,
                              hipStream_t stream) {
  (void)in_sizes; (void)n_in; (void)out_size; (void)ws_size;
  const float* inputs = (const float*)d_in[0];
  const float* Wx[4] = {(const float*)d_in[1], (const float*)d_in[5], (const float*)d_in[9],  (const float*)d_in[13]};
  const float* Wh[4] = {(const float*)d_in[2], (const float*)d_in[6], (const float*)d_in[10], (const float*)d_in[14]};
  const float* bx[4] = {(const float*)d_in[3], (const float*)d_in[7], (const float*)d_in[11], (const float*)d_in[15]};
  const float* bh[4] = {(const float*)d_in[4], (const float*)d_in[8], (const float*)d_in[12], (const float*)d_in[16]};
  const float* Wd = (const float*)d_in[17];
  const float* bd = (const float*)d_in[18];

  char* w = (char*)d_ws;
  auto alloc = [&](size_t bytes) {
    char* p = w;
    w += (bytes + 255) & ~(size_t)255;
    return p;
  };
  // total ~71.6 MiB
  __hip_bfloat16* xin = (__hip_bfloat16*)alloc((size_t)TSTEPS * 16 * 128 * 8 * 2);
  __hip_bfloat16* Wp[4];
  Wp[0] = (__hip_bfloat16*)alloc((size_t)64 * 18 * 8192);
  for (int l = 1; l < 4; ++l)
    Wp[l] = (__hip_bfloat16*)alloc((size_t)64 * 32 * 8192);
  __hip_bfloat16* hout = (__hip_bfloat16*)alloc((size_t)4 * 2 * 128 * 1024 * 2);
  float* hf = (float*)alloc((size_t)4 * 128 * 1024 * 4);
  float* pb = (float*)alloc((size_t)4 * 4096 * 4);

  prep_xin<<<(TSTEPS * 16 * 128) / 256, 256, 0, stream>>>(inputs, xin);
  for (int l = 0; l < 4; ++l) {
    const int Din = (l == 0) ? 128 : 1024;
    const int NKT = (l == 0) ? 18 : 32;
    prep_w<<<4096, 256, 0, stream>>>(Wx[l], Wh[l], Din, Din + 1024, NKT, Wp[l]);
  }
  BiasArgs ba;
  for (int l = 0; l < 4; ++l) { ba.bx[l] = bx[l]; ba.bh[l] = bh[l]; }
  ba.pb = pb;
  prep_bias<<<64, 256, 0, stream>>>(ba);

  GArgs ga;
  ga.xin = xin;
  for (int l = 0; l < 4; ++l) ga.Wp[l] = Wp[l];
  ga.pb = pb;
  ga.hout = hout;
  ga.hf = hf;
  ga.Wd = Wd;
  ga.bd = bd;
  ga.out = (float*)d_out;

  void* kargs[] = { &ga };
  hipLaunchCooperativeKernel((const void*)gru_pipe, dim3(256), dim3(256), kargs, 0, stream);
}

// Round 4
// 7099.940 us; speedup vs baseline: 2.6601x; 2.1259x over previous
//
#include <hip/hip_runtime.h>
#include <hip/hip_bf16.h>
#include <hip/hip_cooperative_groups.h>
#include <math.h>

typedef short bfrag8 __attribute__((ext_vector_type(8)));   // 8 bf16 (4 VGPRs)
typedef float facc4  __attribute__((ext_vector_type(4)));   // MFMA accumulator

#define BATCH   128
#define TSTEPS  256
#define UNITS   1024

// ---------------------------------------------------------------------------
// Dataflow-synced, layer-pipelined GRU stack. No grid.sync (round-3 evidence:
// ~45-50us/step fixed cost of cg::grid.sync over 256 WGs). Per-layer
// generation counters + acquire/release fences instead.
//
// B (weights) packed per layer in streaming order:
//   [nt(64)][kt(NKT)][wn(2)][kh(2)][fb(2)][lane(64)][8 bf16]
// A (x / h state), chunk-major: [k-chunk gk][m(128)][8 bf16]
// h ring buffer: 4 slots per layer (3-step inter-layer slack).
// ---------------------------------------------------------------------------

struct Sync {              // one 256B cacheline per counter
  unsigned int cnt[4][64];
  unsigned int gen[4][64];
};

struct GArgs {
  const __hip_bfloat16* xin;      // [T][16 chunks][128][8] layer-0 input
  const __hip_bfloat16* Wp[4];    // packed weights
  const float* pb;                // packed biases [4][4096] (B-row order)
  __hip_bfloat16* hout;           // h ring [4 layer][4 slot][128 chunks][128][8]
  float* hfin;                    // fp32 final h of layer 3 [128][1024]
  Sync* sy;
  const float* Wd;                // [1024]
  const float* bd;                // [1]
  float* out;                     // [128]
};

// ---------------------------------------------------------------------------
__global__ void prep_xin(const float* __restrict__ in, __hip_bfloat16* __restrict__ xin) {
  const int idx = blockIdx.x * 256 + threadIdx.x;    // chunk id: (t, kg, m)
  if (idx >= TSTEPS * 16 * 128) return;
  const int m  = idx & 127;
  const int kg = (idx >> 7) & 15;
  const int t  = idx >> 11;
  union { __hip_bfloat16 h[8]; uint4 v; } o;
  const float* src = in + ((size_t)m * TSTEPS + t) * 128 + (kg << 3);
  #pragma unroll
  for (int e = 0; e < 8; ++e) o.h[e] = __float2bfloat16(src[e]);
  ((uint4*)xin)[idx] = o.v;
}

__global__ void prep_w(const float* __restrict__ Wx, const float* __restrict__ Wh,
                       int Din, int KS, int NKT, __hip_bfloat16* __restrict__ W) {
  const int p   = blockIdx.x;              // global B-row, 0..4095
  const int tid = threadIdx.x;             // k-chunk along K
  const int k0  = tid << 3;
  if (k0 >= KS) return;
  const int nt = p >> 6, r = p & 63;
  const int wn = r >> 5, fb = (r >> 4) & 1, rl = r & 15;
  const int gg = (r >> 3) & 3, eu = r & 7;
  const int u   = nt * 16 + wn * 8 + eu;   // uh == wn by construction
  const int col = (gg == 0) ? u : (gg == 1) ? (1024 + u) : (2048 + u);
  const int kt = tid >> 3, c = tid & 7, kh = c >> 2, kq = c & 3;
  const int lane = kq * 16 + rl;
  union { __hip_bfloat16 h[8]; uint4 v; } o;
  #pragma unroll
  for (int e = 0; e < 8; ++e) {
    const int k = k0 + e;
    float v = 0.0f;
    if (k < Din) { if (gg != 3) v = Wx[(size_t)k * 3072 + col]; }
    else         { if (gg != 2) v = Wh[(size_t)(k - Din) * 3072 + col]; }
    o.h[e] = __float2bfloat16(v);
  }
  const size_t off16 = (size_t)nt * (NKT * 512)
                     + (size_t)(((kt * 2 + wn) * 2 + kh) * 2 + fb) * 64 + lane;
  ((uint4*)W)[off16] = o.v;
}

struct BiasArgs { const float* bx[4]; const float* bh[4]; float* pb; };

__global__ void prep_bias(BiasArgs ba) {
  const int idx = blockIdx.x * 256 + threadIdx.x;    // l*4096 + p
  if (idx >= 4 * 4096) return;
  const int p = idx & 4095, l = idx >> 12;
  const int nt = p >> 6, r = p & 63;
  const int uh = r >> 5, g = (r >> 3) & 3, eu = r & 7;
  const int u = nt * 16 + uh * 8 + eu;
  const float* bx = ba.bx[l];
  const float* bh = ba.bh[l];
  float v;
  if (g == 0)      v = bx[u] + bh[u];
  else if (g == 1) v = bx[1024 + u] + bh[1024 + u];
  else if (g == 2) v = bx[2048 + u];
  else             v = bh[2048 + u];
  ba.pb[idx] = v;
}

__global__ void prep_zero(__hip_bfloat16* hout, Sync* sy) {
  const int b = blockIdx.x;
  if (b < 1024) {                          // hout: 4*4*128*1024*2B = 262144 uint4
    const uint4 z4 = {0, 0, 0, 0};
    ((uint4*)hout)[b * 256 + threadIdx.x] = z4;
  } else {                                 // sync counters
    unsigned int* p = (unsigned int*)sy;   // 512 uints
    #pragma unroll
    for (int i = 0; i < 2; ++i) p[i * 256 + threadIdx.x] = 0u;
  }
}

// ---------------------------------------------------------------------------
// Main kernel. Grid 256 WGs x 256 thr, 1 WG/CU (cooperative launch only for
// the co-residency guarantee; no grid.sync).
// l = (wg%8)>>1 : each layer's 64 WGs land on an XCD pair (if round-robin).
// WG tile M=128 x N=64 B-rows; 4 waves 2m x 2n; direct-to-VGPR fragments.
// ---------------------------------------------------------------------------
__global__ __launch_bounds__(256) void gru_pipe(GArgs g) {
  __shared__ float lsC[128 * 66];          // C scratch (33.8 KB)

  const int tid  = threadIdx.x;
  const int lane = tid & 63;
  const int wave = tid >> 6;
  const int wm = wave >> 1, wn = wave & 1;
  const int wg = blockIdx.x;
  const int l  = (wg & 7) >> 1;            // layer 0..3 (XCD-pair adjacency)
  const int nt = ((wg >> 3) << 1) | (wg & 1);   // n-tile 0..63 (16 units)
  const int NKT  = l ? 32 : 18;            // k-tiles of 64
  const int DINC = l ? 128 : 16;           // x-part k-chunks (Din/8)
  const float* pbL = g.pb + (l << 12) + (nt << 6);
  const int r15 = lane & 15;
  const int kq  = lane >> 4;

  const char* Bbase = (const char*)g.Wp[l]
                    + (size_t)nt * NKT * 8192 + (size_t)wn * 4096 + (size_t)lane * 16;
  int aoff[4];
  #pragma unroll
  for (int fa = 0; fa < 4; ++fa) aoff[fa] = (wm * 64 + fa * 16 + r15) * 16;

  // persistent fp32 h-state: thread (m=tid&127, blk=tid>>7) owns units
  // nt*16 + blk*8 + 0..7 of row m — private across the whole t-loop.
  float hfr[8];
  #pragma unroll
  for (int e = 0; e < 8; ++e) hfr[e] = 0.0f;
  const int pm  = tid & 127;               // pointwise batch row
  const int blk = tid >> 7;                // pointwise unit block

  unsigned int* cnt = &g.sy->cnt[l][0];
  unsigned int* genL = &g.sy->gen[l][0];
  unsigned int* genU = (l > 0) ? &g.sy->gen[l - 1][0] : nullptr;
  unsigned int* genD = (l < 3) ? &g.sy->gen[l + 1][0] : nullptr;

  const size_t CH = 128 * 1024;            // elements per h slot

  for (int t = 0; t < TSTEPS; ++t) {
    { // --- dataflow spin: 3 parallel pollers, then one acquire fence ---
      if (tid == 0) {
        while (__hip_atomic_load(genL, __ATOMIC_RELAXED, __HIP_MEMORY_SCOPE_AGENT)
               < (unsigned)t) __builtin_amdgcn_s_sleep(4);
      } else if (tid == 1 && genU) {
        while (__hip_atomic_load(genU, __ATOMIC_RELAXED, __HIP_MEMORY_SCOPE_AGENT)
               < (unsigned)(t + 1)) __builtin_amdgcn_s_sleep(4);
      } else if (tid == 2 && genD && t >= 4) {
        while (__hip_atomic_load(genD, __ATOMIC_RELAXED, __HIP_MEMORY_SCOPE_AGENT)
               < (unsigned)(t - 3)) __builtin_amdgcn_s_sleep(4);
      }
      __syncthreads();
      if (tid == 0) __builtin_amdgcn_fence(__ATOMIC_ACQUIRE, "agent");
      __syncthreads();
    }

    const __hip_bfloat16* hA = g.hout + (size_t)((l << 2) | ((t + 3) & 3)) * CH;
    const __hip_bfloat16* xA = l
        ? (g.hout + (size_t)(((l - 1) << 2) | (t & 3)) * CH)
        : (g.xin + (size_t)t * (16 * 128 * 8));

    bfrag8 aP[8], bP[4], aQ[8], bQ[4];

    #define LOADAB(AR, BR, KT)                                               \
      {                                                                      \
        const int kt_ = (KT);                                                \
        _Pragma("unroll")                                                    \
        for (int kh = 0; kh < 2; ++kh) {                                     \
          const int gk = kt_ * 8 + kh * 4 + kq;                              \
          const char* src = (gk < DINC)                                      \
              ? ((const char*)xA + (size_t)gk * 2048)                        \
              : ((const char*)hA + (size_t)(gk - DINC) * 2048);              \
          _Pragma("unroll")                                                  \
          for (int fa = 0; fa < 4; ++fa)                                     \
            AR[kh * 4 + fa] = *(const bfrag8*)(src + aoff[fa]);              \
          _Pragma("unroll")                                                  \
          for (int fb = 0; fb < 2; ++fb)                                     \
            BR[kh * 2 + fb] = *(const bfrag8*)(Bbase + (size_t)kt_ * 8192    \
                                               + kh * 2048 + fb * 1024);     \
        }                                                                    \
      }

    #define DOMFMA(AR, BR)                                                   \
      _Pragma("unroll")                                                      \
      for (int kh = 0; kh < 2; ++kh) {                                       \
        _Pragma("unroll")                                                    \
        for (int fa = 0; fa < 4; ++fa) {                                     \
          acc[fa][0] = __builtin_amdgcn_mfma_f32_16x16x32_bf16(              \
              AR[kh * 4 + fa], BR[kh * 2 + 0], acc[fa][0], 0, 0, 0);         \
          acc[fa][1] = __builtin_amdgcn_mfma_f32_16x16x32_bf16(              \
              AR[kh * 4 + fa], BR[kh * 2 + 1], acc[fa][1], 0, 0, 0);         \
        }                                                                    \
      }

    facc4 acc[4][2];
    #pragma unroll
    for (int fa = 0; fa < 4; ++fa)
      #pragma unroll
      for (int fb = 0; fb < 2; ++fb)
        acc[fa][fb] = (facc4){0, 0, 0, 0};

    LOADAB(aP, bP, 0);
    for (int kt = 0; kt < NKT; kt += 2) {    // NKT even (18 or 32)
      LOADAB(aQ, bQ, kt + 1);
      DOMFMA(aP, bP);
      if (kt + 2 < NKT) LOADAB(aP, bP, kt + 2);
      DOMFMA(aQ, bQ);
    }
    #undef LOADAB
    #undef DOMFMA

    { // C/D layout: col=lane&15 (B side), row=(lane>>4)*4+j (A side)  [m89]
      #pragma unroll
      for (int fa = 0; fa < 4; ++fa) {
        const int crow = (wm << 6) + (fa << 4) + ((lane >> 4) << 2);
        #pragma unroll
        for (int fb = 0; fb < 2; ++fb) {
          const int ccol = (wn << 5) + (fb << 4) + r15;
          #pragma unroll
          for (int j = 0; j < 4; ++j)
            lsC[(crow + j) * 66 + ccol] = acc[fa][fb][j];
        }
      }
    }
    __syncthreads();

    { // pointwise GRU: h-state in persistent VGPRs
      __hip_bfloat16* houtW = g.hout + (size_t)((l << 2) | (t & 3)) * CH;
      const float* cr  = lsC + pm * 66 + blk * 32;
      const float* pbb = pbL + blk * 32;
      union { __hip_bfloat16 h[8]; uint4 v; } ou;
      #pragma unroll
      for (int e = 0; e < 8; ++e) {
        const float gz  = cr[e]      + pbb[e];
        const float gr  = cr[8 + e]  + pbb[8 + e];
        const float gxh = cr[16 + e] + pbb[16 + e];
        const float grh = cr[24 + e] + pbb[24 + e];
        const float z = 1.0f / (1.0f + __expf(-gz));
        const float r = 1.0f / (1.0f + __expf(-gr));
        const float e2 = __expf(2.0f * (gxh + r * grh));
        const float hh = 1.0f - 2.0f / (e2 + 1.0f);   // tanh
        const float hn = z * hfr[e] + (1.0f - z) * hh;
        hfr[e] = hn;
        ou.h[e] = __float2bfloat16(hn);
      }
      ((uint4*)houtW)[(nt * 2 + blk) * 128 + pm] = ou.v;
      if (l == 3 && t == TSTEPS - 1) {     // publish fp32 final h for dense
        float* dst = g.hfin + (size_t)pm * 1024 + (nt << 4) + (blk << 3);
        #pragma unroll
        for (int e = 0; e < 8; ++e) dst[e] = hfr[e];
      }
    }
    __syncthreads();                       // all WG stores drained (per-wave vmcnt)

    if (tid == 0) {                        // arrive: release + publish
      __builtin_amdgcn_fence(__ATOMIC_RELEASE, "agent");
      unsigned int old = __hip_atomic_fetch_add(cnt, 1u, __ATOMIC_RELAXED,
                                                __HIP_MEMORY_SCOPE_AGENT);
      if (old == (unsigned)(64 * (t + 1) - 1))
        __hip_atomic_store(genL, (unsigned)(t + 1), __ATOMIC_RELEASE,
                           __HIP_MEMORY_SCOPE_AGENT);
    }
  }

  // dense head: out[b] = hfin[b][:] . Wd + bd
  if (wg < BATCH) {
    if (tid == 0) {
      while (__hip_atomic_load(&g.sy->gen[3][0], __ATOMIC_RELAXED,
                               __HIP_MEMORY_SCOPE_AGENT) < (unsigned)TSTEPS)
        __builtin_amdgcn_s_sleep(4);
      __builtin_amdgcn_fence(__ATOMIC_ACQUIRE, "agent");
    }
    __syncthreads();
    const float* h = g.hfin + (size_t)wg * 1024;
    float ssum = 0.0f;
    for (int u = tid; u < UNITS; u += 256) ssum += h[u] * g.Wd[u];
    lsC[tid] = ssum;
    __syncthreads();
    for (int off = 128; off; off >>= 1) {
      if (tid < off) lsC[tid] += lsC[tid + off];
      __syncthreads();
    }
    if (tid == 0) g.out[wg] = lsC[0] + g.bd[0];
  }
}

// ---------------------------------------------------------------------------
extern "C" void kernel_launch(void* const* d_in, const int* in_sizes, int n_in,
                              void* d_out, int out_size, void* d_ws, size_t ws_size,
                              hipStream_t stream) {
  (void)in_sizes; (void)n_in; (void)out_size; (void)ws_size;
  const float* inputs = (const float*)d_in[0];
  const float* Wx[4] = {(const float*)d_in[1], (const float*)d_in[5], (const float*)d_in[9],  (const float*)d_in[13]};
  const float* Wh[4] = {(const float*)d_in[2], (const float*)d_in[6], (const float*)d_in[10], (const float*)d_in[14]};
  const float* bx[4] = {(const float*)d_in[3], (const float*)d_in[7], (const float*)d_in[11], (const float*)d_in[15]};
  const float* bh[4] = {(const float*)d_in[4], (const float*)d_in[8], (const float*)d_in[12], (const float*)d_in[16]};
  const float* Wd = (const float*)d_in[17];
  const float* bd = (const float*)d_in[18];

  char* w = (char*)d_ws;
  auto alloc = [&](size_t bytes) {
    char* p = w;
    w += (bytes + 255) & ~(size_t)255;
    return p;
  };
  // total ~72.7 MiB
  __hip_bfloat16* xin = (__hip_bfloat16*)alloc((size_t)TSTEPS * 16 * 128 * 8 * 2);
  __hip_bfloat16* Wp[4];
  Wp[0] = (__hip_bfloat16*)alloc((size_t)64 * 18 * 8192);
  for (int l = 1; l < 4; ++l)
    Wp[l] = (__hip_bfloat16*)alloc((size_t)64 * 32 * 8192);
  __hip_bfloat16* hout = (__hip_bfloat16*)alloc((size_t)4 * 4 * 128 * 1024 * 2);
  float* hfin = (float*)alloc((size_t)128 * 1024 * 4);
  float* pb = (float*)alloc((size_t)4 * 4096 * 4);
  Sync* sy = (Sync*)alloc(sizeof(Sync));

  prep_xin<<<(TSTEPS * 16 * 128) / 256, 256, 0, stream>>>(inputs, xin);
  for (int l = 0; l < 4; ++l) {
    const int Din = (l == 0) ? 128 : 1024;
    const int NKT = (l == 0) ? 18 : 32;
    prep_w<<<4096, 256, 0, stream>>>(Wx[l], Wh[l], Din, Din + 1024, NKT, Wp[l]);
  }
  BiasArgs ba;
  for (int l = 0; l < 4; ++l) { ba.bx[l] = bx[l]; ba.bh[l] = bh[l]; }
  ba.pb = pb;
  prep_bias<<<64, 256, 0, stream>>>(ba);
  prep_zero<<<1025, 256, 0, stream>>>(hout, sy);

  GArgs ga;
  ga.xin = xin;
  for (int l = 0; l < 4; ++l) ga.Wp[l] = Wp[l];
  ga.pb = pb;
  ga.hout = hout;
  ga.hfin = hfin;
  ga.sy = sy;
  ga.Wd = Wd;
  ga.bd = bd;
  ga.out = (float*)d_out;

  void* kargs[] = { &ga };
  hipLaunchCooperativeKernel((const void*)gru_pipe, dim3(256), dim3(256), kargs, 0, stream);
}